// Round 1
// baseline (2137.893 us; speedup 1.0000x reference)
//
#include <hip/hip_runtime.h>
#include <hip/hip_bf16.h>

#define N_NODES 50000
#define N_EDGES 600000
#define F 128
#define TR 32  // rows per GEMM block tile

// ---------------------------------------------------------------------------
// Fuse the two linear layers: Wc = w2 @ w1  (stored transposed: WcT[k][p]),
// bc = w2 @ b1 + b2.
// ---------------------------------------------------------------------------
__global__ void k_fuse(const float* __restrict__ w1, const float* __restrict__ b1,
                       const float* __restrict__ w2, const float* __restrict__ b2,
                       float* __restrict__ WcT, float* __restrict__ bc) {
    int p = blockIdx.x;   // output row of Wc
    int j = threadIdx.x;  // input col of Wc
    float s = 0.f;
    for (int o = 0; o < F; ++o) s = fmaf(w2[p * F + o], w1[o * F + j], s);
    WcT[j * F + p] = s;  // transposed store for the GEMM kernel
    if (j == 0) {
        float t = b2[p];
        for (int o = 0; o < F; ++o) t = fmaf(w2[p * F + o], b1[o], t);
        bc[p] = t;
    }
}

// ---------------------------------------------------------------------------
// Y[n][p] = sum_k X[n][k] * Wc[p][k] + bc[p];  also writes A = Y (self-loop
// accumulator init). WcT (64KB) + transposed X tile (16KB) in dynamic LDS.
// 256 threads: thread (rg,cg) computes 4 rows x 4 cols micro-tile.
// ---------------------------------------------------------------------------
__global__ __launch_bounds__(256, 2)
void k_gemm(const float* __restrict__ X, const float* __restrict__ WcT_g,
            const float* __restrict__ bc_g, float* __restrict__ Y,
            float* __restrict__ A, int n_rows) {
    extern __shared__ float lds[];
    float* Ws = lds;             // [128][128]  Ws[k*F + p] = Wc[p][k]
    float* Xs = lds + F * F;     // [128][TR]   Xs[k*TR + r]
    const int tid = threadIdx.x;
    const int row0 = blockIdx.x * TR;

    // stage WcT: 16384 floats, float4 loads
    {
        const float4* src = (const float4*)WcT_g;
        float4* dst = (float4*)Ws;
        for (int i = tid; i < F * F / 4; i += 256) dst[i] = src[i];
    }
    // stage X rows [row0, row0+TR) transposed into Xs
    for (int i = tid; i < TR * F / 4; i += 256) {
        int r = i / (F / 4);
        int k4 = i % (F / 4);
        float4 v = {0.f, 0.f, 0.f, 0.f};
        if (row0 + r < n_rows) v = ((const float4*)(X + (size_t)(row0 + r) * F))[k4];
        Xs[(4 * k4 + 0) * TR + r] = v.x;
        Xs[(4 * k4 + 1) * TR + r] = v.y;
        Xs[(4 * k4 + 2) * TR + r] = v.z;
        Xs[(4 * k4 + 3) * TR + r] = v.w;
    }
    __syncthreads();

    const int cg = tid & 31;  // cols 4cg..4cg+3
    const int rg = tid >> 5;  // rows 4rg..4rg+3
    float acc[4][4] = {{0.f}};

#pragma unroll 4
    for (int k = 0; k < F; ++k) {
        const float4 xv = *(const float4*)&Xs[k * TR + 4 * rg];
        const float4 wv = *(const float4*)&Ws[k * F + 4 * cg];
        acc[0][0] = fmaf(xv.x, wv.x, acc[0][0]);
        acc[0][1] = fmaf(xv.x, wv.y, acc[0][1]);
        acc[0][2] = fmaf(xv.x, wv.z, acc[0][2]);
        acc[0][3] = fmaf(xv.x, wv.w, acc[0][3]);
        acc[1][0] = fmaf(xv.y, wv.x, acc[1][0]);
        acc[1][1] = fmaf(xv.y, wv.y, acc[1][1]);
        acc[1][2] = fmaf(xv.y, wv.z, acc[1][2]);
        acc[1][3] = fmaf(xv.y, wv.w, acc[1][3]);
        acc[2][0] = fmaf(xv.z, wv.x, acc[2][0]);
        acc[2][1] = fmaf(xv.z, wv.y, acc[2][1]);
        acc[2][2] = fmaf(xv.z, wv.z, acc[2][2]);
        acc[2][3] = fmaf(xv.z, wv.w, acc[2][3]);
        acc[3][0] = fmaf(xv.w, wv.x, acc[3][0]);
        acc[3][1] = fmaf(xv.w, wv.y, acc[3][1]);
        acc[3][2] = fmaf(xv.w, wv.z, acc[3][2]);
        acc[3][3] = fmaf(xv.w, wv.w, acc[3][3]);
    }

    const float4 bias = ((const float4*)bc_g)[cg];
#pragma unroll
    for (int i = 0; i < 4; ++i) {
        int row = row0 + 4 * rg + i;
        if (row < n_rows) {
            float4 o;
            o.x = acc[i][0] + bias.x;
            o.y = acc[i][1] + bias.y;
            o.z = acc[i][2] + bias.z;
            o.w = acc[i][3] + bias.w;
            ((float4*)(Y + (size_t)row * F))[cg] = o;
            ((float4*)(A + (size_t)row * F))[cg] = o;
        }
    }
}

// ---------------------------------------------------------------------------
// A[dst[e]] += H[src[e]]  for all edges. 32 threads per edge, float4 gather,
// 4 hardware fp32 atomics per thread.
// ---------------------------------------------------------------------------
__global__ __launch_bounds__(256)
void k_scatter(const float* __restrict__ H, const int* __restrict__ src,
               const int* __restrict__ dst, float* __restrict__ A) {
    int g = blockIdx.x * 256 + threadIdx.x;
    int e = g >> 5;
    int c = g & 31;
    if (e >= N_EDGES) return;
    int s = src[e];
    int d = dst[e];
    float4 v = ((const float4*)(H + (size_t)s * F))[c];
    float* out = A + (size_t)d * F + 4 * c;
    unsafeAtomicAdd(out + 0, v.x);
    unsafeAtomicAdd(out + 1, v.y);
    unsafeAtomicAdd(out + 2, v.z);
    unsafeAtomicAdd(out + 3, v.w);
}

// ---------------------------------------------------------------------------
// In-place row-wise log_softmax. One wave (64 lanes) per row; 2 floats/lane.
// ---------------------------------------------------------------------------
__global__ __launch_bounds__(256)
void k_logsoftmax(float* __restrict__ Y, int n_rows) {
    int wid = threadIdx.x >> 6;
    int lane = threadIdx.x & 63;
    int row = blockIdx.x * 4 + wid;
    if (row >= n_rows) return;
    float2* rowp = (float2*)(Y + (size_t)row * F);
    float2 v = rowp[lane];
    float m = fmaxf(v.x, v.y);
#pragma unroll
    for (int o = 32; o; o >>= 1) m = fmaxf(m, __shfl_xor(m, o));
    float s = expf(v.x - m) + expf(v.y - m);
#pragma unroll
    for (int o = 32; o; o >>= 1) s += __shfl_xor(s, o);
    float lse = m + logf(s);
    v.x -= lse;
    v.y -= lse;
    rowp[lane] = v;
}

extern "C" void kernel_launch(void* const* d_in, const int* in_sizes, int n_in,
                              void* d_out, int out_size, void* d_ws, size_t ws_size,
                              hipStream_t stream) {
    const float* x  = (const float*)d_in[0];
    const int* ei   = (const int*)d_in[1];   // [2][N_EDGES]
    const float* w1 = (const float*)d_in[2];
    const float* b1 = (const float*)d_in[3];
    const float* w2 = (const float*)d_in[4];
    const float* b2 = (const float*)d_in[5];
    float* out = (float*)d_out;

    const int* src = ei;             // edge_index[0]
    const int* dst = ei + N_EDGES;   // edge_index[1]

    float* ws   = (float*)d_ws;
    float* WcT  = ws;                       // 16384 floats
    float* bc   = ws + 16384;               // 128 floats
    float* hbuf = ws + 16512;               // 6.4M floats (linear output)
    float* abuf = hbuf + (size_t)N_NODES * F;  // 6.4M floats (accumulator)

    const int gemm_grid = (N_NODES + TR - 1) / TR;      // 1563
    const size_t gemm_lds = (size_t)(F * F + F * TR) * sizeof(float);  // 80KB
    const int scat_grid = (N_EDGES * 32) / 256;         // 75000
    const int lsm_grid = (N_NODES + 3) / 4;             // 12500

    // fused weights
    k_fuse<<<128, 128, 0, stream>>>(w1, b1, w2, b2, WcT, bc);

    // conv 1: linear -> hbuf, self-loop init -> abuf; scatter edges into abuf
    k_gemm<<<gemm_grid, 256, gemm_lds, stream>>>(x, WcT, bc, hbuf, abuf, N_NODES);
    k_scatter<<<scat_grid, 256, 0, stream>>>(hbuf, src, dst, abuf);

    // conv 2: linear(abuf) -> hbuf, self-loop init -> out; scatter into out
    k_gemm<<<gemm_grid, 256, gemm_lds, stream>>>(abuf, WcT, bc, hbuf, out, N_NODES);
    k_scatter<<<scat_grid, 256, 0, stream>>>(hbuf, src, dst, out);

    // log_softmax in place on out
    k_logsoftmax<<<lsm_grid, 256, 0, stream>>>(out, N_NODES);
}

// Round 2
// 245.678 us; speedup vs baseline: 8.7020x; 8.7020x over previous
//
#include <hip/hip_runtime.h>
#include <hip/hip_bf16.h>

#define N_NODES 50000
#define N_EDGES 600000
#define F 128
#define TR 32      // rows per GEMM block tile
#define BCAP 64    // per-node incoming-edge bucket capacity (P(deg>64) ~ 1e-10)

// ---------------------------------------------------------------------------
// Fuse the two linear layers: Wc = w2 @ w1  (stored transposed: WcT[k][p]),
// bc = w2 @ b1 + b2.
// ---------------------------------------------------------------------------
__global__ void k_fuse(const float* __restrict__ w1, const float* __restrict__ b1,
                       const float* __restrict__ w2, const float* __restrict__ b2,
                       float* __restrict__ WcT, float* __restrict__ bc) {
    int p = blockIdx.x;   // output row of Wc
    int j = threadIdx.x;  // input col of Wc
    float s = 0.f;
    for (int o = 0; o < F; ++o) s = fmaf(w2[p * F + o], w1[o * F + j], s);
    WcT[j * F + p] = s;  // transposed store for the GEMM kernel
    if (j == 0) {
        float t = b2[p];
        for (int o = 0; o < F; ++o) t = fmaf(w2[p * F + o], b1[o], t);
        bc[p] = t;
    }
}

// ---------------------------------------------------------------------------
// Bucket-CSR build: slot = cnt[dst]++; bucket[dst*BCAP+slot] = src.
// cnt must be zeroed beforehand (hipMemsetAsync).
// ---------------------------------------------------------------------------
__global__ __launch_bounds__(256)
void k_fill(const int* __restrict__ src, const int* __restrict__ dst,
            int* __restrict__ cnt, int* __restrict__ bucket) {
    int e = blockIdx.x * 256 + threadIdx.x;
    if (e >= N_EDGES) return;
    int d = dst[e];
    int slot = atomicAdd(&cnt[d], 1);
    if (slot < BCAP) bucket[d * BCAP + slot] = src[e];
}

// ---------------------------------------------------------------------------
// Y[n][p] = sum_k X[n][k] * Wc[p][k] + bc[p].
// Safe to run in-place (Y == X): each block stages its own 32 input rows into
// LDS before writing, and blocks touch disjoint row ranges.
// ---------------------------------------------------------------------------
__global__ __launch_bounds__(256, 2)
void k_gemm(const float* __restrict__ X, const float* __restrict__ WcT_g,
            const float* __restrict__ bc_g, float* __restrict__ Y, int n_rows) {
    extern __shared__ float lds[];
    float* Ws = lds;             // [128][128]  Ws[k*F + p] = Wc[p][k]
    float* Xs = lds + F * F;     // [128][TR]   Xs[k*TR + r]
    const int tid = threadIdx.x;
    const int row0 = blockIdx.x * TR;

    {
        const float4* src = (const float4*)WcT_g;
        float4* dst = (float4*)Ws;
        for (int i = tid; i < F * F / 4; i += 256) dst[i] = src[i];
    }
    for (int i = tid; i < TR * F / 4; i += 256) {
        int r = i / (F / 4);
        int k4 = i % (F / 4);
        float4 v = {0.f, 0.f, 0.f, 0.f};
        if (row0 + r < n_rows) v = ((const float4*)(X + (size_t)(row0 + r) * F))[k4];
        Xs[(4 * k4 + 0) * TR + r] = v.x;
        Xs[(4 * k4 + 1) * TR + r] = v.y;
        Xs[(4 * k4 + 2) * TR + r] = v.z;
        Xs[(4 * k4 + 3) * TR + r] = v.w;
    }
    __syncthreads();

    const int cg = tid & 31;  // cols 4cg..4cg+3
    const int rg = tid >> 5;  // rows 4rg..4rg+3
    float acc[4][4] = {{0.f}};

#pragma unroll 4
    for (int k = 0; k < F; ++k) {
        const float4 xv = *(const float4*)&Xs[k * TR + 4 * rg];
        const float4 wv = *(const float4*)&Ws[k * F + 4 * cg];
        acc[0][0] = fmaf(xv.x, wv.x, acc[0][0]);
        acc[0][1] = fmaf(xv.x, wv.y, acc[0][1]);
        acc[0][2] = fmaf(xv.x, wv.z, acc[0][2]);
        acc[0][3] = fmaf(xv.x, wv.w, acc[0][3]);
        acc[1][0] = fmaf(xv.y, wv.x, acc[1][0]);
        acc[1][1] = fmaf(xv.y, wv.y, acc[1][1]);
        acc[1][2] = fmaf(xv.y, wv.z, acc[1][2]);
        acc[1][3] = fmaf(xv.y, wv.w, acc[1][3]);
        acc[2][0] = fmaf(xv.z, wv.x, acc[2][0]);
        acc[2][1] = fmaf(xv.z, wv.y, acc[2][1]);
        acc[2][2] = fmaf(xv.z, wv.z, acc[2][2]);
        acc[2][3] = fmaf(xv.z, wv.w, acc[2][3]);
        acc[3][0] = fmaf(xv.w, wv.x, acc[3][0]);
        acc[3][1] = fmaf(xv.w, wv.y, acc[3][1]);
        acc[3][2] = fmaf(xv.w, wv.z, acc[3][2]);
        acc[3][3] = fmaf(xv.w, wv.w, acc[3][3]);
    }

    const float4 bias = ((const float4*)bc_g)[cg];
#pragma unroll
    for (int i = 0; i < 4; ++i) {
        int row = row0 + 4 * rg + i;
        if (row < n_rows) {
            float4 o;
            o.x = acc[i][0] + bias.x;
            o.y = acc[i][1] + bias.y;
            o.z = acc[i][2] + bias.z;
            o.w = acc[i][3] + bias.w;
            ((float4*)(Y + (size_t)row * F))[cg] = o;
        }
    }
}

// ---------------------------------------------------------------------------
// O[n] = H[n] + sum_{e: dst[e]==n} H[src[e]].  One wave per node; lane holds
// 2 floats (float2 = 8B/lane -> one coalesced 512B read per gathered row).
// Bucket entries read 4-at-a-time for memory-level parallelism.
// ---------------------------------------------------------------------------
__global__ __launch_bounds__(256)
void k_agg(const float* __restrict__ H, const int* __restrict__ cnt,
           const int* __restrict__ bucket, float* __restrict__ O, int n_rows) {
    int wid = threadIdx.x >> 6;
    int lane = threadIdx.x & 63;
    int node = blockIdx.x * 4 + wid;
    if (node >= n_rows) return;

    int deg = cnt[node];
    if (deg > BCAP) deg = BCAP;
    float2 acc = ((const float2*)(H + (size_t)node * F))[lane];  // self-loop

    const int* bk = bucket + node * BCAP;
    int i = 0;
    for (; i + 4 <= deg; i += 4) {
        int4 s4 = *(const int4*)(bk + i);
        float2 v0 = ((const float2*)(H + (size_t)s4.x * F))[lane];
        float2 v1 = ((const float2*)(H + (size_t)s4.y * F))[lane];
        float2 v2 = ((const float2*)(H + (size_t)s4.z * F))[lane];
        float2 v3 = ((const float2*)(H + (size_t)s4.w * F))[lane];
        acc.x += v0.x + v1.x + v2.x + v3.x;
        acc.y += v0.y + v1.y + v2.y + v3.y;
    }
    for (; i < deg; ++i) {
        int s = bk[i];
        float2 v = ((const float2*)(H + (size_t)s * F))[lane];
        acc.x += v.x;
        acc.y += v.y;
    }
    ((float2*)(O + (size_t)node * F))[lane] = acc;
}

// ---------------------------------------------------------------------------
// Row-wise log_softmax, src -> dst. One wave per row, 2 floats/lane.
// ---------------------------------------------------------------------------
__global__ __launch_bounds__(256)
void k_logsoftmax(const float* __restrict__ Yin, float* __restrict__ Yout, int n_rows) {
    int wid = threadIdx.x >> 6;
    int lane = threadIdx.x & 63;
    int row = blockIdx.x * 4 + wid;
    if (row >= n_rows) return;
    float2 v = ((const float2*)(Yin + (size_t)row * F))[lane];
    float m = fmaxf(v.x, v.y);
#pragma unroll
    for (int o = 32; o; o >>= 1) m = fmaxf(m, __shfl_xor(m, o));
    float s = expf(v.x - m) + expf(v.y - m);
#pragma unroll
    for (int o = 32; o; o >>= 1) s += __shfl_xor(s, o);
    float lse = m + logf(s);
    v.x -= lse;
    v.y -= lse;
    ((float2*)(Yout + (size_t)row * F))[lane] = v;
}

extern "C" void kernel_launch(void* const* d_in, const int* in_sizes, int n_in,
                              void* d_out, int out_size, void* d_ws, size_t ws_size,
                              hipStream_t stream) {
    const float* x  = (const float*)d_in[0];
    const int* ei   = (const int*)d_in[1];   // [2][N_EDGES], converted to int32
    const float* w1 = (const float*)d_in[2];
    const float* b1 = (const float*)d_in[3];
    const float* w2 = (const float*)d_in[4];
    const float* b2 = (const float*)d_in[5];
    float* out = (float*)d_out;

    const int* src = ei;             // edge_index[0]
    const int* dst = ei + N_EDGES;   // edge_index[1]

    // workspace layout (16B-aligned chunks)
    float* ws     = (float*)d_ws;
    float* WcT    = ws;                        // 16384 floats
    float* bc     = ws + 16384;                // 128 floats (+pad to 16512)
    int*   cnt    = (int*)(ws + 16512);        // 50000 ints (pad to 50048)
    int*   bucket = (int*)(ws + 16512) + 50048;            // 50000*64 ints
    float* buf    = (float*)((int*)(ws + 16512) + 50048 + N_NODES * BCAP);  // 6.4M floats

    const int gemm_grid = (N_NODES + TR - 1) / TR;                      // 1563
    const size_t gemm_lds = (size_t)(F * F + F * TR) * sizeof(float);   // 80KB
    const int fill_grid = (N_EDGES + 255) / 256;
    const int node_grid = (N_NODES + 3) / 4;

    // fused weights + bucket-CSR (built once, reused for both phases)
    k_fuse<<<128, 128, 0, stream>>>(w1, b1, w2, b2, WcT, bc);
    hipMemsetAsync(cnt, 0, N_NODES * sizeof(int), stream);
    k_fill<<<fill_grid, 256, 0, stream>>>(src, dst, cnt, bucket);

    // conv 1: linear(x) -> buf; aggregate(buf) -> out (used as scratch)
    k_gemm<<<gemm_grid, 256, gemm_lds, stream>>>(x, WcT, bc, buf, N_NODES);
    k_agg<<<node_grid, 256, 0, stream>>>(buf, cnt, bucket, out, N_NODES);

    // conv 2: linear(out) -> out (in-place); aggregate(out) -> buf
    k_gemm<<<gemm_grid, 256, gemm_lds, stream>>>(out, WcT, bc, out, N_NODES);
    k_agg<<<node_grid, 256, 0, stream>>>(out, cnt, bucket, buf, N_NODES);

    // log_softmax: buf -> out
    k_logsoftmax<<<node_grid, 256, 0, stream>>>(buf, out, N_NODES);
}

// Round 3
// 169.162 us; speedup vs baseline: 12.6382x; 1.4523x over previous
//
#include <hip/hip_runtime.h>
#include <hip/hip_bf16.h>

#define N_NODES 50000
#define N_EDGES 600000
#define F 128
#define TR 32      // rows per GEMM block tile
#define BCAP 64    // per-node incoming-edge bucket capacity (P(deg>64) ~ 0)

typedef unsigned short bf16_t;

__device__ inline float bf2f(bf16_t u) {
    union { unsigned int i; float f; } c;
    c.i = ((unsigned int)u) << 16;
    return c.f;
}
__device__ inline bf16_t f2bf(float f) {  // round-to-nearest-even
    union { float f; unsigned int i; } c;
    c.f = f;
    unsigned int lsb = (c.i >> 16) & 1;
    c.i += 0x7fffu + lsb;
    return (bf16_t)(c.i >> 16);
}

// ---------------------------------------------------------------------------
// Stage 1 of weight fusion: Wc = w2 @ w1 (plain [p][j]), bc = w2@b1 + b2.
// ---------------------------------------------------------------------------
__global__ void k_fuse(const float* __restrict__ w1, const float* __restrict__ b1,
                       const float* __restrict__ w2, const float* __restrict__ b2,
                       float* __restrict__ Wc, float* __restrict__ bc) {
    int p = blockIdx.x;
    int j = threadIdx.x;
    float s = 0.f;
    for (int o = 0; o < F; ++o) s = fmaf(w2[p * F + o], w1[o * F + j], s);
    Wc[p * F + j] = s;
    if (j == 0) {
        float t = b2[p];
        for (int o = 0; o < F; ++o) t = fmaf(w2[p * F + o], b1[o], t);
        bc[p] = t;
    }
}

// ---------------------------------------------------------------------------
// Stage 2: M[k][p] = (W^T W^T)[k][p] = sum_o Wc[p][o] * Wc[o][k]   (64KB)
//          v1[p]  = sum_o Wc[p][o] * bc[o]
// ---------------------------------------------------------------------------
__global__ void k_fuse2(const float* __restrict__ Wc, const float* __restrict__ bc,
                        float* __restrict__ M, float* __restrict__ v1) {
    int k = blockIdx.x;
    int p = threadIdx.x;
    float s = 0.f;
    for (int o = 0; o < F; ++o) s = fmaf(Wc[p * F + o], Wc[o * F + k], s);
    M[k * F + p] = s;
    if (k == 0) {
        float t = 0.f;
        for (int o = 0; o < F; ++o) t = fmaf(Wc[p * F + o], bc[o], t);
        v1[p] = t;
    }
}

// ---------------------------------------------------------------------------
// Bucket-CSR build: slot = cnt[dst]++; bucket[dst*BCAP+slot] = src.
// ---------------------------------------------------------------------------
__global__ __launch_bounds__(256)
void k_fill(const int* __restrict__ src, const int* __restrict__ dst,
            int* __restrict__ cnt, int* __restrict__ bucket) {
    int e = blockIdx.x * 256 + threadIdx.x;
    if (e >= N_EDGES) return;
    int d = dst[e];
    int slot = atomicAdd(&cnt[d], 1);
    if (slot < BCAP) bucket[d * BCAP + slot] = src[e];
}

// ---------------------------------------------------------------------------
// sd[n] = d_n + sum_{s in bucket[n]} d_s,  d_i = cnt[i] + 1.
// ---------------------------------------------------------------------------
__global__ __launch_bounds__(256)
void k_sd(const int* __restrict__ cnt, const int* __restrict__ bucket,
          float* __restrict__ sd) {
    int n = blockIdx.x * 256 + threadIdx.x;
    if (n >= N_NODES) return;
    int deg = cnt[n];
    int dg = deg < BCAP ? deg : BCAP;
    int s = deg + 1;
    const int* bk = bucket + n * BCAP;
    for (int i = 0; i < dg; ++i) s += cnt[bk[i]] + 1;
    sd[n] = (float)s;
}

// ---------------------------------------------------------------------------
// g[n][p] = sum_k x[n][k] * M[k][p]   (fp32 compute, bf16 store)
// M staged to LDS [128][128]; X tile transposed into LDS with XOR swizzle
// (col = r ^ (k & 28)) to kill the 32-way staging bank conflict. Reads of Xs
// are half-wave broadcasts, so the swizzle is free on the read side.
// ---------------------------------------------------------------------------
__global__ __launch_bounds__(256, 2)
void k_gemm(const float* __restrict__ X, const float* __restrict__ M_g,
            bf16_t* __restrict__ G, int n_rows) {
    extern __shared__ float lds[];
    float* Ws = lds;             // [128][128]   Ws[k*F + p] = M[k][p]
    float* Xs = lds + F * F;     // [128][TR]    Xs[k*TR + (r ^ (k&28))]
    const int tid = threadIdx.x;
    const int row0 = blockIdx.x * TR;

    {
        const float4* src = (const float4*)M_g;
        float4* dst = (float4*)Ws;
        for (int i = tid; i < F * F / 4; i += 256) dst[i] = src[i];
    }
    for (int i = tid; i < TR * F / 4; i += 256) {
        int r = i >> 5;          // 0..31
        int k4 = i & 31;         // float4 index along k
        float4 v = {0.f, 0.f, 0.f, 0.f};
        if (row0 + r < n_rows) v = ((const float4*)(X + (size_t)(row0 + r) * F))[k4];
        int kk = 4 * k4;
        int c = r ^ (kk & 28);   // same perm for kk..kk+3 (low 2 bits unused)
        Xs[(kk + 0) * TR + c] = v.x;
        Xs[(kk + 1) * TR + c] = v.y;
        Xs[(kk + 2) * TR + c] = v.z;
        Xs[(kk + 3) * TR + c] = v.w;
    }
    __syncthreads();

    const int cg = tid & 31;  // cols 4cg..4cg+3
    const int rg = tid >> 5;  // rows 4rg..4rg+3
    float acc[4][4] = {{0.f}};

#pragma unroll 4
    for (int k = 0; k < F; ++k) {
        const float4 xv = *(const float4*)&Xs[k * TR + ((4 * rg) ^ (k & 28))];
        const float4 wv = *(const float4*)&Ws[k * F + 4 * cg];
        acc[0][0] = fmaf(xv.x, wv.x, acc[0][0]);
        acc[0][1] = fmaf(xv.x, wv.y, acc[0][1]);
        acc[0][2] = fmaf(xv.x, wv.z, acc[0][2]);
        acc[0][3] = fmaf(xv.x, wv.w, acc[0][3]);
        acc[1][0] = fmaf(xv.y, wv.x, acc[1][0]);
        acc[1][1] = fmaf(xv.y, wv.y, acc[1][1]);
        acc[1][2] = fmaf(xv.y, wv.z, acc[1][2]);
        acc[1][3] = fmaf(xv.y, wv.w, acc[1][3]);
        acc[2][0] = fmaf(xv.z, wv.x, acc[2][0]);
        acc[2][1] = fmaf(xv.z, wv.y, acc[2][1]);
        acc[2][2] = fmaf(xv.z, wv.z, acc[2][2]);
        acc[2][3] = fmaf(xv.z, wv.w, acc[2][3]);
        acc[3][0] = fmaf(xv.w, wv.x, acc[3][0]);
        acc[3][1] = fmaf(xv.w, wv.y, acc[3][1]);
        acc[3][2] = fmaf(xv.w, wv.z, acc[3][2]);
        acc[3][3] = fmaf(xv.w, wv.w, acc[3][3]);
    }

#pragma unroll
    for (int i = 0; i < 4; ++i) {
        int row = row0 + 4 * rg + i;
        if (row < n_rows) {
            ushort4 o;
            o.x = f2bf(acc[i][0]);
            o.y = f2bf(acc[i][1]);
            o.z = f2bf(acc[i][2]);
            o.w = f2bf(acc[i][3]);
            *(ushort4*)(G + (size_t)row * F + 4 * cg) = o;
        }
    }
}

// ---------------------------------------------------------------------------
// O[n] = H[n] + sum_{e: dst[e]==n} H[src[e]]  (bf16 in, fp32 acc, bf16 out).
// One wave per node; lane holds cols 2l..2l+1 (4B/lane -> 256B coalesced row).
// ---------------------------------------------------------------------------
__global__ __launch_bounds__(256)
void k_agg(const bf16_t* __restrict__ H, const int* __restrict__ cnt,
           const int* __restrict__ bucket, bf16_t* __restrict__ O, int n_rows) {
    int wid = threadIdx.x >> 6;
    int lane = threadIdx.x & 63;
    int node = blockIdx.x * 4 + wid;
    if (node >= n_rows) return;

    int deg = cnt[node];
    if (deg > BCAP) deg = BCAP;
    ushort2 u = ((const ushort2*)(H + (size_t)node * F))[lane];
    float ax = bf2f(u.x), ay = bf2f(u.y);

    const int* bk = bucket + node * BCAP;
    int i = 0;
    for (; i + 4 <= deg; i += 4) {
        int4 s4 = *(const int4*)(bk + i);
        ushort2 u0 = ((const ushort2*)(H + (size_t)s4.x * F))[lane];
        ushort2 u1 = ((const ushort2*)(H + (size_t)s4.y * F))[lane];
        ushort2 u2 = ((const ushort2*)(H + (size_t)s4.z * F))[lane];
        ushort2 u3 = ((const ushort2*)(H + (size_t)s4.w * F))[lane];
        ax += bf2f(u0.x) + bf2f(u1.x) + bf2f(u2.x) + bf2f(u3.x);
        ay += bf2f(u0.y) + bf2f(u1.y) + bf2f(u2.y) + bf2f(u3.y);
    }
    for (; i < deg; ++i) {
        ushort2 uv = ((const ushort2*)(H + (size_t)bk[i] * F))[lane];
        ax += bf2f(uv.x);
        ay += bf2f(uv.y);
    }
    ushort2 o;
    o.x = f2bf(ax);
    o.y = f2bf(ay);
    ((ushort2*)(O + (size_t)node * F))[lane] = o;
}

// ---------------------------------------------------------------------------
// Final: out[n] = log_softmax( H_agg[n] + sd_n*v1 + d_n*bc ), fp32 out.
// Same gather structure as k_agg, epilogue fused (wave already owns the row).
// ---------------------------------------------------------------------------
__global__ __launch_bounds__(256)
void k_agg_ep(const bf16_t* __restrict__ H, const int* __restrict__ cnt,
              const int* __restrict__ bucket, const float* __restrict__ sd,
              const float* __restrict__ v1, const float* __restrict__ bc,
              float* __restrict__ O, int n_rows) {
    int wid = threadIdx.x >> 6;
    int lane = threadIdx.x & 63;
    int node = blockIdx.x * 4 + wid;
    if (node >= n_rows) return;

    int deg_t = cnt[node];
    int deg = deg_t < BCAP ? deg_t : BCAP;
    ushort2 u = ((const ushort2*)(H + (size_t)node * F))[lane];
    float ax = bf2f(u.x), ay = bf2f(u.y);

    const int* bk = bucket + node * BCAP;
    int i = 0;
    for (; i + 4 <= deg; i += 4) {
        int4 s4 = *(const int4*)(bk + i);
        ushort2 u0 = ((const ushort2*)(H + (size_t)s4.x * F))[lane];
        ushort2 u1 = ((const ushort2*)(H + (size_t)s4.y * F))[lane];
        ushort2 u2 = ((const ushort2*)(H + (size_t)s4.z * F))[lane];
        ushort2 u3 = ((const ushort2*)(H + (size_t)s4.w * F))[lane];
        ax += bf2f(u0.x) + bf2f(u1.x) + bf2f(u2.x) + bf2f(u3.x);
        ay += bf2f(u0.y) + bf2f(u1.y) + bf2f(u2.y) + bf2f(u3.y);
    }
    for (; i < deg; ++i) {
        ushort2 uv = ((const ushort2*)(H + (size_t)bk[i] * F))[lane];
        ax += bf2f(uv.x);
        ay += bf2f(uv.y);
    }

    // rank-1 bias terms
    float dn = (float)(deg_t + 1);
    float sdn = sd[node];
    float2 v1v = ((const float2*)v1)[lane];
    float2 bcv = ((const float2*)bc)[lane];
    ax += sdn * v1v.x + dn * bcv.x;
    ay += sdn * v1v.y + dn * bcv.y;

    // log_softmax across the wave (2 values/lane)
    float m = fmaxf(ax, ay);
#pragma unroll
    for (int o = 32; o; o >>= 1) m = fmaxf(m, __shfl_xor(m, o));
    float s = expf(ax - m) + expf(ay - m);
#pragma unroll
    for (int o = 32; o; o >>= 1) s += __shfl_xor(s, o);
    float lse = m + logf(s);
    float2 o2;
    o2.x = ax - lse;
    o2.y = ay - lse;
    ((float2*)(O + (size_t)node * F))[lane] = o2;
}

extern "C" void kernel_launch(void* const* d_in, const int* in_sizes, int n_in,
                              void* d_out, int out_size, void* d_ws, size_t ws_size,
                              hipStream_t stream) {
    const float* x  = (const float*)d_in[0];
    const int* ei   = (const int*)d_in[1];
    const float* w1 = (const float*)d_in[2];
    const float* b1 = (const float*)d_in[3];
    const float* w2 = (const float*)d_in[4];
    const float* b2 = (const float*)d_in[5];
    float* out = (float*)d_out;

    const int* src = ei;
    const int* dst = ei + N_EDGES;

    // workspace layout (float offsets, all 16B aligned)
    float* ws     = (float*)d_ws;
    float* Wc     = ws;                        // 16384
    float* M      = ws + 16384;                // 16384
    float* bc     = ws + 32768;                // 128
    float* v1     = ws + 32896;                // 128
    float* sd     = ws + 33024;                // 50048
    int*   cnt    = (int*)(ws + 83072);        // 50048
    int*   bucket = (int*)(ws + 133120);       // 3,200,000
    bf16_t* g     = (bf16_t*)(ws + 3333120);   // 6.4M bf16 (3.2M floats)
    bf16_t* a1    = (bf16_t*)(ws + 6533120);   // 6.4M bf16

    const int gemm_grid = (N_NODES + TR - 1) / TR;
    const size_t gemm_lds = (size_t)(F * F + F * TR) * sizeof(float);  // 80KB
    const int fill_grid = (N_EDGES + 255) / 256;
    const int node_grid = (N_NODES + 3) / 4;
    const int nthr_grid = (N_NODES + 255) / 256;

    k_fuse<<<128, 128, 0, stream>>>(w1, b1, w2, b2, Wc, bc);
    k_fuse2<<<128, 128, 0, stream>>>(Wc, bc, M, v1);
    hipMemsetAsync(cnt, 0, N_NODES * sizeof(int), stream);
    k_fill<<<fill_grid, 256, 0, stream>>>(src, dst, cnt, bucket);
    k_sd<<<nthr_grid, 256, 0, stream>>>(cnt, bucket, sd);

    // g = x * M  (single GEMM)
    k_gemm<<<gemm_grid, 256, gemm_lds, stream>>>(x, M, g, N_NODES);
    // a1 = S * g
    k_agg<<<node_grid, 256, 0, stream>>>(g, cnt, bucket, a1, N_NODES);
    // out = log_softmax(S * a1 + sd*v1^T + d*bc^T)
    k_agg_ep<<<node_grid, 256, 0, stream>>>(a1, cnt, bucket, sd, v1, bc, out, N_NODES);
}

// Round 4
// 130.053 us; speedup vs baseline: 16.4387x; 1.3007x over previous
//
#include <hip/hip_runtime.h>
#include <hip/hip_bf16.h>

#define N_NODES 50000
#define N_EDGES 600000
#define F 128
#define BCAP 64    // per-node incoming-edge bucket capacity (P(deg>64) ~ 0)

typedef unsigned short bf16_t;
typedef __attribute__((ext_vector_type(8))) short short8v;
typedef __attribute__((ext_vector_type(8))) unsigned short ushort8v;
typedef __attribute__((ext_vector_type(4))) float f32x4;

__device__ inline float bf2f(bf16_t u) {
    union { unsigned int i; float f; } c;
    c.i = ((unsigned int)u) << 16;
    return c.f;
}
__device__ inline bf16_t f2bf(float f) {  // round-to-nearest-even
    union { float f; unsigned int i; } c;
    c.f = f;
    unsigned int lsb = (c.i >> 16) & 1;
    c.i += 0x7fffu + lsb;
    return (bf16_t)(c.i >> 16);
}

// ---------------------------------------------------------------------------
// Stage 1 of weight fusion: Wc = w2 @ w1 (plain [p][j]), bc = w2@b1 + b2.
// ---------------------------------------------------------------------------
__global__ void k_fuse(const float* __restrict__ w1, const float* __restrict__ b1,
                       const float* __restrict__ w2, const float* __restrict__ b2,
                       float* __restrict__ Wc, float* __restrict__ bc) {
    int p = blockIdx.x;
    int j = threadIdx.x;
    float s = 0.f;
    for (int o = 0; o < F; ++o) s = fmaf(w2[p * F + o], w1[o * F + j], s);
    Wc[p * F + j] = s;
    if (j == 0) {
        float t = b2[p];
        for (int o = 0; o < F; ++o) t = fmaf(w2[p * F + o], b1[o], t);
        bc[p] = t;
    }
}

// ---------------------------------------------------------------------------
// Stage 2: Mbf[p][k] = (W^T W^T)[k][p] in bf16 (B-operand layout for MFMA),
//          v1[p] = sum_o Wc[p][o] * bc[o].
// ---------------------------------------------------------------------------
__global__ void k_fuse2(const float* __restrict__ Wc, const float* __restrict__ bc,
                        bf16_t* __restrict__ Mbf, float* __restrict__ v1) {
    int k = blockIdx.x;
    int p = threadIdx.x;
    float s = 0.f;
    for (int o = 0; o < F; ++o) s = fmaf(Wc[p * F + o], Wc[o * F + k], s);
    Mbf[p * F + k] = f2bf(s);   // [p][k]: contiguous along k for B fragments
    if (k == 0) {
        float t = 0.f;
        for (int o = 0; o < F; ++o) t = fmaf(Wc[p * F + o], bc[o], t);
        v1[p] = t;
    }
}

// ---------------------------------------------------------------------------
// Bucket-CSR build.
// ---------------------------------------------------------------------------
__global__ __launch_bounds__(256)
void k_fill(const int* __restrict__ src, const int* __restrict__ dst,
            int* __restrict__ cnt, int* __restrict__ bucket) {
    int e = blockIdx.x * 256 + threadIdx.x;
    if (e >= N_EDGES) return;
    int d = dst[e];
    int slot = atomicAdd(&cnt[d], 1);
    if (slot < BCAP) bucket[d * BCAP + slot] = src[e];
}

// ---------------------------------------------------------------------------
// sd[n] = d_n + sum_{s in bucket[n]} d_s,  d_i = cnt[i] + 1.
// ---------------------------------------------------------------------------
__global__ __launch_bounds__(256)
void k_sd(const int* __restrict__ cnt, const int* __restrict__ bucket,
          float* __restrict__ sd) {
    int n = blockIdx.x * 256 + threadIdx.x;
    if (n >= N_NODES) return;
    int deg = cnt[n];
    int dg = deg < BCAP ? deg : BCAP;
    int s = deg + 1;
    const int* bk = bucket + n * BCAP;
    for (int i = 0; i < dg; ++i) s += cnt[bk[i]] + 1;
    sd[n] = (float)s;
}

// ---------------------------------------------------------------------------
// g = x * M via bf16 MFMA. Block: 64 rows x 128 cols, 4 waves (2x2), each
// wave 32x64 = 2x4 tiles of mfma_f32_16x16x32_bf16. LDS tiles XOR-swizzled
// in 8-bf16 chunks (chunk ^= row&7) -> conflict-minimal ds_read_b128.
// Fragment maps (m89-verified): A row=l&15,k=8*(l>>4)+j; B col=l&15 same k;
// C/D col=l&15,row=4*(l>>4)+reg.
// ---------------------------------------------------------------------------
__global__ __launch_bounds__(256, 2)
void k_gemm_mfma(const float* __restrict__ X, const bf16_t* __restrict__ Mbf,
                 bf16_t* __restrict__ G, int n_rows) {
    extern __shared__ unsigned short smem[];
    unsigned short* Xs = smem;          // [64][128] bf16, swizzled
    unsigned short* Ms = smem + 8192;   // [128][128] bf16, swizzled
    const int tid = threadIdx.x;
    const int row0 = blockIdx.x * 64;

    // stage M: 128 rows x 16 chunks(8 bf16)
    for (int idx = tid; idx < 2048; idx += 256) {
        int p = idx >> 4, c = idx & 15;
        ushort8v v = ((const ushort8v*)Mbf)[idx];
        *(ushort8v*)&Ms[p * 128 + (((c ^ (p & 7)) << 3))] = v;
    }
    // stage X: 64 rows x 16 chunks, fp32 -> bf16
    for (int idx = tid; idx < 1024; idx += 256) {
        int r = idx >> 4, c = idx & 15;
        int grow = row0 + r;
        float4 va = {0.f, 0.f, 0.f, 0.f}, vb = {0.f, 0.f, 0.f, 0.f};
        if (grow < n_rows) {
            const float4* xr = (const float4*)(X + (size_t)grow * F);
            va = xr[2 * c];
            vb = xr[2 * c + 1];
        }
        ushort8v u;
        u[0] = f2bf(va.x); u[1] = f2bf(va.y); u[2] = f2bf(va.z); u[3] = f2bf(va.w);
        u[4] = f2bf(vb.x); u[5] = f2bf(vb.y); u[6] = f2bf(vb.z); u[7] = f2bf(vb.w);
        *(ushort8v*)&Xs[r * 128 + (((c ^ (r & 7)) << 3))] = u;
    }
    __syncthreads();

    const int wid = tid >> 6;
    const int lane = tid & 63;
    const int wr = wid >> 1;       // wave row (0..1): rows wr*32+0..31
    const int wc = wid & 1;        // wave col (0..1): cols wc*64+0..63
    const int l15 = lane & 15;
    const int l4 = lane >> 4;
    const int sw = (l15 & 7);      // swizzle key, same for A and B rows here

    f32x4 acc[2][4] = {};

#pragma unroll
    for (int kc = 0; kc < 4; ++kc) {
        const int cS = ((kc * 4 + l4) ^ sw) << 3;  // swizzled k-chunk byte base
        short8v a0 = *(const short8v*)&Xs[(wr * 32 + 0 * 16 + l15) * 128 + cS];
        short8v a1 = *(const short8v*)&Xs[(wr * 32 + 1 * 16 + l15) * 128 + cS];
        short8v b0 = *(const short8v*)&Ms[(wc * 64 + 0 * 16 + l15) * 128 + cS];
        short8v b1 = *(const short8v*)&Ms[(wc * 64 + 1 * 16 + l15) * 128 + cS];
        short8v b2 = *(const short8v*)&Ms[(wc * 64 + 2 * 16 + l15) * 128 + cS];
        short8v b3 = *(const short8v*)&Ms[(wc * 64 + 3 * 16 + l15) * 128 + cS];
        acc[0][0] = __builtin_amdgcn_mfma_f32_16x16x32_bf16(a0, b0, acc[0][0], 0, 0, 0);
        acc[0][1] = __builtin_amdgcn_mfma_f32_16x16x32_bf16(a0, b1, acc[0][1], 0, 0, 0);
        acc[0][2] = __builtin_amdgcn_mfma_f32_16x16x32_bf16(a0, b2, acc[0][2], 0, 0, 0);
        acc[0][3] = __builtin_amdgcn_mfma_f32_16x16x32_bf16(a0, b3, acc[0][3], 0, 0, 0);
        acc[1][0] = __builtin_amdgcn_mfma_f32_16x16x32_bf16(a1, b0, acc[1][0], 0, 0, 0);
        acc[1][1] = __builtin_amdgcn_mfma_f32_16x16x32_bf16(a1, b1, acc[1][1], 0, 0, 0);
        acc[1][2] = __builtin_amdgcn_mfma_f32_16x16x32_bf16(a1, b2, acc[1][2], 0, 0, 0);
        acc[1][3] = __builtin_amdgcn_mfma_f32_16x16x32_bf16(a1, b3, acc[1][3], 0, 0, 0);
    }

#pragma unroll
    for (int mt = 0; mt < 2; ++mt) {
#pragma unroll
        for (int nt = 0; nt < 4; ++nt) {
#pragma unroll
            for (int r = 0; r < 4; ++r) {
                int grow = row0 + wr * 32 + mt * 16 + l4 * 4 + r;
                if (grow < n_rows) {
                    int gcol = wc * 64 + nt * 16 + l15;
                    G[(size_t)grow * F + gcol] = f2bf(acc[mt][nt][r]);
                }
            }
        }
    }
}

// ---------------------------------------------------------------------------
// O[n] = H[n] + sum_{s in bucket[n]} H[s].  Half-wave (32 lanes) per node,
// lane holds 4 cols (ushort4 = 8B -> 256B row per half-wave), unroll 8.
// ---------------------------------------------------------------------------
__global__ __launch_bounds__(256)
void k_agg(const bf16_t* __restrict__ H, const int* __restrict__ cnt,
           const int* __restrict__ bucket, bf16_t* __restrict__ O, int n_rows) {
    int tid = threadIdx.x;
    int lane = tid & 31;
    int node = blockIdx.x * 8 + (tid >> 5);
    if (node >= n_rows) return;

    int deg = cnt[node];
    if (deg > BCAP) deg = BCAP;
    ushort4 u = ((const ushort4*)(H + (size_t)node * F))[lane];
    float a0 = bf2f(u.x), a1 = bf2f(u.y), a2 = bf2f(u.z), a3 = bf2f(u.w);

    const int* bk = bucket + node * BCAP;
    int i = 0;
    for (; i + 8 <= deg; i += 8) {
        int4 s4 = *(const int4*)(bk + i);
        int4 s5 = *(const int4*)(bk + i + 4);
        ushort4 u0 = ((const ushort4*)(H + (size_t)s4.x * F))[lane];
        ushort4 u1 = ((const ushort4*)(H + (size_t)s4.y * F))[lane];
        ushort4 u2 = ((const ushort4*)(H + (size_t)s4.z * F))[lane];
        ushort4 u3 = ((const ushort4*)(H + (size_t)s4.w * F))[lane];
        ushort4 u4 = ((const ushort4*)(H + (size_t)s5.x * F))[lane];
        ushort4 u5 = ((const ushort4*)(H + (size_t)s5.y * F))[lane];
        ushort4 u6 = ((const ushort4*)(H + (size_t)s5.z * F))[lane];
        ushort4 u7 = ((const ushort4*)(H + (size_t)s5.w * F))[lane];
        a0 += bf2f(u0.x) + bf2f(u1.x) + bf2f(u2.x) + bf2f(u3.x)
            + bf2f(u4.x) + bf2f(u5.x) + bf2f(u6.x) + bf2f(u7.x);
        a1 += bf2f(u0.y) + bf2f(u1.y) + bf2f(u2.y) + bf2f(u3.y)
            + bf2f(u4.y) + bf2f(u5.y) + bf2f(u6.y) + bf2f(u7.y);
        a2 += bf2f(u0.z) + bf2f(u1.z) + bf2f(u2.z) + bf2f(u3.z)
            + bf2f(u4.z) + bf2f(u5.z) + bf2f(u6.z) + bf2f(u7.z);
        a3 += bf2f(u0.w) + bf2f(u1.w) + bf2f(u2.w) + bf2f(u3.w)
            + bf2f(u4.w) + bf2f(u5.w) + bf2f(u6.w) + bf2f(u7.w);
    }
    for (; i + 4 <= deg; i += 4) {
        int4 s4 = *(const int4*)(bk + i);
        ushort4 u0 = ((const ushort4*)(H + (size_t)s4.x * F))[lane];
        ushort4 u1 = ((const ushort4*)(H + (size_t)s4.y * F))[lane];
        ushort4 u2 = ((const ushort4*)(H + (size_t)s4.z * F))[lane];
        ushort4 u3 = ((const ushort4*)(H + (size_t)s4.w * F))[lane];
        a0 += bf2f(u0.x) + bf2f(u1.x) + bf2f(u2.x) + bf2f(u3.x);
        a1 += bf2f(u0.y) + bf2f(u1.y) + bf2f(u2.y) + bf2f(u3.y);
        a2 += bf2f(u0.z) + bf2f(u1.z) + bf2f(u2.z) + bf2f(u3.z);
        a3 += bf2f(u0.w) + bf2f(u1.w) + bf2f(u2.w) + bf2f(u3.w);
    }
    for (; i < deg; ++i) {
        ushort4 uv = ((const ushort4*)(H + (size_t)bk[i] * F))[lane];
        a0 += bf2f(uv.x); a1 += bf2f(uv.y); a2 += bf2f(uv.z); a3 += bf2f(uv.w);
    }
    ushort4 o;
    o.x = f2bf(a0); o.y = f2bf(a1); o.z = f2bf(a2); o.w = f2bf(a3);
    ((ushort4*)(O + (size_t)node * F))[lane] = o;
}

// ---------------------------------------------------------------------------
// Final: out[n] = log_softmax( (S*H)[n] + sd_n*v1 + d_n*bc ).  Same gather
// structure as k_agg; epilogue reduces over the 32-lane half-wave.
// ---------------------------------------------------------------------------
__global__ __launch_bounds__(256)
void k_agg_ep(const bf16_t* __restrict__ H, const int* __restrict__ cnt,
              const int* __restrict__ bucket, const float* __restrict__ sd,
              const float* __restrict__ v1, const float* __restrict__ bc,
              float* __restrict__ O, int n_rows) {
    int tid = threadIdx.x;
    int lane = tid & 31;
    int node = blockIdx.x * 8 + (tid >> 5);
    if (node >= n_rows) return;

    int deg_t = cnt[node];
    int deg = deg_t < BCAP ? deg_t : BCAP;
    ushort4 u = ((const ushort4*)(H + (size_t)node * F))[lane];
    float a0 = bf2f(u.x), a1 = bf2f(u.y), a2 = bf2f(u.z), a3 = bf2f(u.w);

    const int* bk = bucket + node * BCAP;
    int i = 0;
    for (; i + 8 <= deg; i += 8) {
        int4 s4 = *(const int4*)(bk + i);
        int4 s5 = *(const int4*)(bk + i + 4);
        ushort4 u0 = ((const ushort4*)(H + (size_t)s4.x * F))[lane];
        ushort4 u1 = ((const ushort4*)(H + (size_t)s4.y * F))[lane];
        ushort4 u2 = ((const ushort4*)(H + (size_t)s4.z * F))[lane];
        ushort4 u3 = ((const ushort4*)(H + (size_t)s4.w * F))[lane];
        ushort4 u4 = ((const ushort4*)(H + (size_t)s5.x * F))[lane];
        ushort4 u5 = ((const ushort4*)(H + (size_t)s5.y * F))[lane];
        ushort4 u6 = ((const ushort4*)(H + (size_t)s5.z * F))[lane];
        ushort4 u7 = ((const ushort4*)(H + (size_t)s5.w * F))[lane];
        a0 += bf2f(u0.x) + bf2f(u1.x) + bf2f(u2.x) + bf2f(u3.x)
            + bf2f(u4.x) + bf2f(u5.x) + bf2f(u6.x) + bf2f(u7.x);
        a1 += bf2f(u0.y) + bf2f(u1.y) + bf2f(u2.y) + bf2f(u3.y)
            + bf2f(u4.y) + bf2f(u5.y) + bf2f(u6.y) + bf2f(u7.y);
        a2 += bf2f(u0.z) + bf2f(u1.z) + bf2f(u2.z) + bf2f(u3.z)
            + bf2f(u4.z) + bf2f(u5.z) + bf2f(u6.z) + bf2f(u7.z);
        a3 += bf2f(u0.w) + bf2f(u1.w) + bf2f(u2.w) + bf2f(u3.w)
            + bf2f(u4.w) + bf2f(u5.w) + bf2f(u6.w) + bf2f(u7.w);
    }
    for (; i + 4 <= deg; i += 4) {
        int4 s4 = *(const int4*)(bk + i);
        ushort4 u0 = ((const ushort4*)(H + (size_t)s4.x * F))[lane];
        ushort4 u1 = ((const ushort4*)(H + (size_t)s4.y * F))[lane];
        ushort4 u2 = ((const ushort4*)(H + (size_t)s4.z * F))[lane];
        ushort4 u3 = ((const ushort4*)(H + (size_t)s4.w * F))[lane];
        a0 += bf2f(u0.x) + bf2f(u1.x) + bf2f(u2.x) + bf2f(u3.x);
        a1 += bf2f(u0.y) + bf2f(u1.y) + bf2f(u2.y) + bf2f(u3.y);
        a2 += bf2f(u0.z) + bf2f(u1.z) + bf2f(u2.z) + bf2f(u3.z);
        a3 += bf2f(u0.w) + bf2f(u1.w) + bf2f(u2.w) + bf2f(u3.w);
    }
    for (; i < deg; ++i) {
        ushort4 uv = ((const ushort4*)(H + (size_t)bk[i] * F))[lane];
        a0 += bf2f(uv.x); a1 += bf2f(uv.y); a2 += bf2f(uv.z); a3 += bf2f(uv.w);
    }

    float dn = (float)(deg_t + 1);
    float sdn = sd[node];
    float4 v1v = ((const float4*)v1)[lane];
    float4 bcv = ((const float4*)bc)[lane];
    a0 += sdn * v1v.x + dn * bcv.x;
    a1 += sdn * v1v.y + dn * bcv.y;
    a2 += sdn * v1v.z + dn * bcv.z;
    a3 += sdn * v1v.w + dn * bcv.w;

    float m = fmaxf(fmaxf(a0, a1), fmaxf(a2, a3));
#pragma unroll
    for (int o = 16; o; o >>= 1) m = fmaxf(m, __shfl_xor(m, o));
    float s = expf(a0 - m) + expf(a1 - m) + expf(a2 - m) + expf(a3 - m);
#pragma unroll
    for (int o = 16; o; o >>= 1) s += __shfl_xor(s, o);
    float lse = m + logf(s);
    float4 o4;
    o4.x = a0 - lse; o4.y = a1 - lse; o4.z = a2 - lse; o4.w = a3 - lse;
    ((float4*)(O + (size_t)node * F))[lane] = o4;
}

extern "C" void kernel_launch(void* const* d_in, const int* in_sizes, int n_in,
                              void* d_out, int out_size, void* d_ws, size_t ws_size,
                              hipStream_t stream) {
    const float* x  = (const float*)d_in[0];
    const int* ei   = (const int*)d_in[1];
    const float* w1 = (const float*)d_in[2];
    const float* b1 = (const float*)d_in[3];
    const float* w2 = (const float*)d_in[4];
    const float* b2 = (const float*)d_in[5];
    float* out = (float*)d_out;

    const int* src = ei;
    const int* dst = ei + N_EDGES;

    // workspace layout (float offsets, 16B aligned)
    float* ws     = (float*)d_ws;
    float* Wc     = ws;                          // 16384
    float* bc     = ws + 16384;                  // 128
    float* v1     = ws + 16512;                  // 128
    float* sd     = ws + 16640;                  // 50048
    bf16_t* Mbf   = (bf16_t*)(ws + 66688);       // 16384 bf16 (8192 f)
    int*   cnt    = (int*)(ws + 74880);          // 50048
    int*   bucket = (int*)(ws + 124928);         // 3,200,000
    bf16_t* g     = (bf16_t*)(ws + 3324928);     // 6.4M bf16
    bf16_t* a1    = (bf16_t*)(ws + 6524928);     // 6.4M bf16

    const int gemm_grid = (N_NODES + 63) / 64;                 // 782
    const size_t gemm_lds = (64 + 128) * 128 * sizeof(bf16_t); // 48KB
    const int fill_grid = (N_EDGES + 255) / 256;
    const int node_grid = (N_NODES + 7) / 8;                   // 6250
    const int nthr_grid = (N_NODES + 255) / 256;

    k_fuse<<<128, 128, 0, stream>>>(w1, b1, w2, b2, Wc, bc);
    k_fuse2<<<128, 128, 0, stream>>>(Wc, bc, Mbf, v1);
    hipMemsetAsync(cnt, 0, N_NODES * sizeof(int), stream);
    k_fill<<<fill_grid, 256, 0, stream>>>(src, dst, cnt, bucket);
    k_sd<<<nthr_grid, 256, 0, stream>>>(cnt, bucket, sd);

    // g = x * M  (bf16 MFMA)
    k_gemm_mfma<<<gemm_grid, 256, gemm_lds, stream>>>(x, Mbf, g, N_NODES);
    // a1 = S * g
    k_agg<<<node_grid, 256, 0, stream>>>(g, cnt, bucket, a1, N_NODES);
    // out = log_softmax(S * a1 + sd*v1^T + d*bc^T)
    k_agg_ep<<<node_grid, 256, 0, stream>>>(a1, cnt, bucket, sd, v1, bc, out, N_NODES);
}

// Round 5
// 126.780 us; speedup vs baseline: 16.8630x; 1.0258x over previous
//
#include <hip/hip_runtime.h>
#include <hip/hip_bf16.h>

#define N_NODES 50000
#define N_EDGES 600000
#define F 128
#define BCAP 64    // per-node incoming-edge bucket capacity (P(deg>64) ~ 0)

typedef unsigned short bf16_t;
typedef __attribute__((ext_vector_type(8))) short short8v;
typedef __attribute__((ext_vector_type(8))) unsigned short ushort8v;
typedef __attribute__((ext_vector_type(4))) float f32x4;

__device__ inline float bf2f(bf16_t u) {
    union { unsigned int i; float f; } c;
    c.i = ((unsigned int)u) << 16;
    return c.f;
}
__device__ inline bf16_t f2bf(float f) {  // round-to-nearest-even
    union { float f; unsigned int i; } c;
    c.f = f;
    unsigned int lsb = (c.i >> 16) & 1;
    c.i += 0x7fffu + lsb;
    return (bf16_t)(c.i >> 16);
}

// ---------------------------------------------------------------------------
// Stage 1 of weight fusion: Wc = w2 @ w1 (plain [p][j]), bc = w2@b1 + b2.
// Also zeroes cnt[] (replaces a 42us rocclr fillBuffer dispatch).
// ---------------------------------------------------------------------------
__global__ void k_fuse(const float* __restrict__ w1, const float* __restrict__ b1,
                       const float* __restrict__ w2, const float* __restrict__ b2,
                       float* __restrict__ Wc, float* __restrict__ bc,
                       int* __restrict__ cnt) {
    int p = blockIdx.x;
    int j = threadIdx.x;
    // zero the degree counters
    int gid = p * 128 + j;
    for (int i = gid; i < N_NODES; i += 128 * 128) cnt[i] = 0;

    float s = 0.f;
    for (int o = 0; o < F; ++o) s = fmaf(w2[p * F + o], w1[o * F + j], s);
    Wc[p * F + j] = s;
    if (j == 0) {
        float t = b2[p];
        for (int o = 0; o < F; ++o) t = fmaf(w2[p * F + o], b1[o], t);
        bc[p] = t;
    }
}

// ---------------------------------------------------------------------------
// Stage 2: Mbf[p][k] = (W^T W^T)[k][p] in bf16 (B-operand layout for MFMA),
//          v1[p] = sum_o Wc[p][o] * bc[o].
// ---------------------------------------------------------------------------
__global__ void k_fuse2(const float* __restrict__ Wc, const float* __restrict__ bc,
                        bf16_t* __restrict__ Mbf, float* __restrict__ v1) {
    int k = blockIdx.x;
    int p = threadIdx.x;
    float s = 0.f;
    for (int o = 0; o < F; ++o) s = fmaf(Wc[p * F + o], Wc[o * F + k], s);
    Mbf[p * F + k] = f2bf(s);   // [p][k]: contiguous along k for B fragments
    if (k == 0) {
        float t = 0.f;
        for (int o = 0; o < F; ++o) t = fmaf(Wc[p * F + o], bc[o], t);
        v1[p] = t;
    }
}

// ---------------------------------------------------------------------------
// Bucket-CSR build.
// ---------------------------------------------------------------------------
__global__ __launch_bounds__(256)
void k_fill(const int* __restrict__ src, const int* __restrict__ dst,
            int* __restrict__ cnt, int* __restrict__ bucket) {
    int e = blockIdx.x * 256 + threadIdx.x;
    if (e >= N_EDGES) return;
    int d = dst[e];
    int slot = atomicAdd(&cnt[d], 1);
    if (slot < BCAP) bucket[d * BCAP + slot] = src[e];
}

// ---------------------------------------------------------------------------
// g = x * M via bf16 MFMA. Block: 64 rows x 128 cols, 4 waves (2x2), each
// wave 32x64 = 2x4 tiles of mfma_f32_16x16x32_bf16. LDS tiles XOR-swizzled
// in 8-bf16 chunks (chunk ^= row&7) -> conflict-minimal ds_read_b128.
// ---------------------------------------------------------------------------
__global__ __launch_bounds__(256, 2)
void k_gemm_mfma(const float* __restrict__ X, const bf16_t* __restrict__ Mbf,
                 bf16_t* __restrict__ G, int n_rows) {
    extern __shared__ unsigned short smem[];
    unsigned short* Xs = smem;          // [64][128] bf16, swizzled
    unsigned short* Ms = smem + 8192;   // [128][128] bf16, swizzled
    const int tid = threadIdx.x;
    const int row0 = blockIdx.x * 64;

    for (int idx = tid; idx < 2048; idx += 256) {
        int p = idx >> 4, c = idx & 15;
        ushort8v v = ((const ushort8v*)Mbf)[idx];
        *(ushort8v*)&Ms[p * 128 + (((c ^ (p & 7)) << 3))] = v;
    }
    for (int idx = tid; idx < 1024; idx += 256) {
        int r = idx >> 4, c = idx & 15;
        int grow = row0 + r;
        float4 va = {0.f, 0.f, 0.f, 0.f}, vb = {0.f, 0.f, 0.f, 0.f};
        if (grow < n_rows) {
            const float4* xr = (const float4*)(X + (size_t)grow * F);
            va = xr[2 * c];
            vb = xr[2 * c + 1];
        }
        ushort8v u;
        u[0] = f2bf(va.x); u[1] = f2bf(va.y); u[2] = f2bf(va.z); u[3] = f2bf(va.w);
        u[4] = f2bf(vb.x); u[5] = f2bf(vb.y); u[6] = f2bf(vb.z); u[7] = f2bf(vb.w);
        *(ushort8v*)&Xs[r * 128 + (((c ^ (r & 7)) << 3))] = u;
    }
    __syncthreads();

    const int wid = tid >> 6;
    const int lane = tid & 63;
    const int wr = wid >> 1;
    const int wc = wid & 1;
    const int l15 = lane & 15;
    const int l4 = lane >> 4;
    const int sw = (l15 & 7);

    f32x4 acc[2][4] = {};

#pragma unroll
    for (int kc = 0; kc < 4; ++kc) {
        const int cS = ((kc * 4 + l4) ^ sw) << 3;
        short8v a0 = *(const short8v*)&Xs[(wr * 32 + 0 * 16 + l15) * 128 + cS];
        short8v a1 = *(const short8v*)&Xs[(wr * 32 + 1 * 16 + l15) * 128 + cS];
        short8v b0 = *(const short8v*)&Ms[(wc * 64 + 0 * 16 + l15) * 128 + cS];
        short8v b1 = *(const short8v*)&Ms[(wc * 64 + 1 * 16 + l15) * 128 + cS];
        short8v b2 = *(const short8v*)&Ms[(wc * 64 + 2 * 16 + l15) * 128 + cS];
        short8v b3 = *(const short8v*)&Ms[(wc * 64 + 3 * 16 + l15) * 128 + cS];
        acc[0][0] = __builtin_amdgcn_mfma_f32_16x16x32_bf16(a0, b0, acc[0][0], 0, 0, 0);
        acc[0][1] = __builtin_amdgcn_mfma_f32_16x16x32_bf16(a0, b1, acc[0][1], 0, 0, 0);
        acc[0][2] = __builtin_amdgcn_mfma_f32_16x16x32_bf16(a0, b2, acc[0][2], 0, 0, 0);
        acc[0][3] = __builtin_amdgcn_mfma_f32_16x16x32_bf16(a0, b3, acc[0][3], 0, 0, 0);
        acc[1][0] = __builtin_amdgcn_mfma_f32_16x16x32_bf16(a1, b0, acc[1][0], 0, 0, 0);
        acc[1][1] = __builtin_amdgcn_mfma_f32_16x16x32_bf16(a1, b1, acc[1][1], 0, 0, 0);
        acc[1][2] = __builtin_amdgcn_mfma_f32_16x16x32_bf16(a1, b2, acc[1][2], 0, 0, 0);
        acc[1][3] = __builtin_amdgcn_mfma_f32_16x16x32_bf16(a1, b3, acc[1][3], 0, 0, 0);
    }

#pragma unroll
    for (int mt = 0; mt < 2; ++mt) {
#pragma unroll
        for (int nt = 0; nt < 4; ++nt) {
#pragma unroll
            for (int r = 0; r < 4; ++r) {
                int grow = row0 + wr * 32 + mt * 16 + l4 * 4 + r;
                if (grow < n_rows) {
                    int gcol = wc * 64 + nt * 16 + l15;
                    G[(size_t)grow * F + gcol] = f2bf(acc[mt][nt][r]);
                }
            }
        }
    }
}

// ---------------------------------------------------------------------------
// O[n] = H[n] + sum_{s in bucket[n]} H[s].  Half-wave (32 lanes) per node,
// lane holds 4 cols (ushort4 = 8B -> 256B row per half-wave), unroll 8.
// ---------------------------------------------------------------------------
__global__ __launch_bounds__(256)
void k_agg(const bf16_t* __restrict__ H, const int* __restrict__ cnt,
           const int* __restrict__ bucket, bf16_t* __restrict__ O, int n_rows) {
    int tid = threadIdx.x;
    int lane = tid & 31;
    int node = blockIdx.x * 8 + (tid >> 5);
    if (node >= n_rows) return;

    int deg = cnt[node];
    if (deg > BCAP) deg = BCAP;
    ushort4 u = ((const ushort4*)(H + (size_t)node * F))[lane];
    float a0 = bf2f(u.x), a1 = bf2f(u.y), a2 = bf2f(u.z), a3 = bf2f(u.w);

    const int* bk = bucket + node * BCAP;
    int i = 0;
    for (; i + 8 <= deg; i += 8) {
        int4 s4 = *(const int4*)(bk + i);
        int4 s5 = *(const int4*)(bk + i + 4);
        ushort4 u0 = ((const ushort4*)(H + (size_t)s4.x * F))[lane];
        ushort4 u1 = ((const ushort4*)(H + (size_t)s4.y * F))[lane];
        ushort4 u2 = ((const ushort4*)(H + (size_t)s4.z * F))[lane];
        ushort4 u3 = ((const ushort4*)(H + (size_t)s4.w * F))[lane];
        ushort4 u4 = ((const ushort4*)(H + (size_t)s5.x * F))[lane];
        ushort4 u5 = ((const ushort4*)(H + (size_t)s5.y * F))[lane];
        ushort4 u6 = ((const ushort4*)(H + (size_t)s5.z * F))[lane];
        ushort4 u7 = ((const ushort4*)(H + (size_t)s5.w * F))[lane];
        a0 += bf2f(u0.x) + bf2f(u1.x) + bf2f(u2.x) + bf2f(u3.x)
            + bf2f(u4.x) + bf2f(u5.x) + bf2f(u6.x) + bf2f(u7.x);
        a1 += bf2f(u0.y) + bf2f(u1.y) + bf2f(u2.y) + bf2f(u3.y)
            + bf2f(u4.y) + bf2f(u5.y) + bf2f(u6.y) + bf2f(u7.y);
        a2 += bf2f(u0.z) + bf2f(u1.z) + bf2f(u2.z) + bf2f(u3.z)
            + bf2f(u4.z) + bf2f(u5.z) + bf2f(u6.z) + bf2f(u7.z);
        a3 += bf2f(u0.w) + bf2f(u1.w) + bf2f(u2.w) + bf2f(u3.w)
            + bf2f(u4.w) + bf2f(u5.w) + bf2f(u6.w) + bf2f(u7.w);
    }
    for (; i + 4 <= deg; i += 4) {
        int4 s4 = *(const int4*)(bk + i);
        ushort4 u0 = ((const ushort4*)(H + (size_t)s4.x * F))[lane];
        ushort4 u1 = ((const ushort4*)(H + (size_t)s4.y * F))[lane];
        ushort4 u2 = ((const ushort4*)(H + (size_t)s4.z * F))[lane];
        ushort4 u3 = ((const ushort4*)(H + (size_t)s4.w * F))[lane];
        a0 += bf2f(u0.x) + bf2f(u1.x) + bf2f(u2.x) + bf2f(u3.x);
        a1 += bf2f(u0.y) + bf2f(u1.y) + bf2f(u2.y) + bf2f(u3.y);
        a2 += bf2f(u0.z) + bf2f(u1.z) + bf2f(u2.z) + bf2f(u3.z);
        a3 += bf2f(u0.w) + bf2f(u1.w) + bf2f(u2.w) + bf2f(u3.w);
    }
    for (; i < deg; ++i) {
        ushort4 uv = ((const ushort4*)(H + (size_t)bk[i] * F))[lane];
        a0 += bf2f(uv.x); a1 += bf2f(uv.y); a2 += bf2f(uv.z); a3 += bf2f(uv.w);
    }
    ushort4 o;
    o.x = f2bf(a0); o.y = f2bf(a1); o.z = f2bf(a2); o.w = f2bf(a3);
    ((ushort4*)(O + (size_t)node * F))[lane] = o;
}

// ---------------------------------------------------------------------------
// Final: out[n] = log_softmax( (S*H)[n] + sd_n*v1 + d_n*bc ).  sd_n computed
// inline: lanes cooperatively gather cnt[s] over the bucket, shuffle-reduced.
// ---------------------------------------------------------------------------
__global__ __launch_bounds__(256)
void k_agg_ep(const bf16_t* __restrict__ H, const int* __restrict__ cnt,
              const int* __restrict__ bucket,
              const float* __restrict__ v1, const float* __restrict__ bc,
              float* __restrict__ O, int n_rows) {
    int tid = threadIdx.x;
    int lane = tid & 31;
    int node = blockIdx.x * 8 + (tid >> 5);
    if (node >= n_rows) return;

    int deg_t = cnt[node];
    int deg = deg_t < BCAP ? deg_t : BCAP;
    ushort4 u = ((const ushort4*)(H + (size_t)node * F))[lane];
    float a0 = bf2f(u.x), a1 = bf2f(u.y), a2 = bf2f(u.z), a3 = bf2f(u.w);

    const int* bk = bucket + node * BCAP;

    // inline sd: lane j sums (cnt[bk[j]]+1) for j, j+32; reduced below
    int sdi = (lane == 0) ? (deg_t + 1) : 0;
    for (int j = lane; j < deg; j += 32) sdi += cnt[bk[j]] + 1;

    int i = 0;
    for (; i + 8 <= deg; i += 8) {
        int4 s4 = *(const int4*)(bk + i);
        int4 s5 = *(const int4*)(bk + i + 4);
        ushort4 u0 = ((const ushort4*)(H + (size_t)s4.x * F))[lane];
        ushort4 u1 = ((const ushort4*)(H + (size_t)s4.y * F))[lane];
        ushort4 u2 = ((const ushort4*)(H + (size_t)s4.z * F))[lane];
        ushort4 u3 = ((const ushort4*)(H + (size_t)s4.w * F))[lane];
        ushort4 u4 = ((const ushort4*)(H + (size_t)s5.x * F))[lane];
        ushort4 u5 = ((const ushort4*)(H + (size_t)s5.y * F))[lane];
        ushort4 u6 = ((const ushort4*)(H + (size_t)s5.z * F))[lane];
        ushort4 u7 = ((const ushort4*)(H + (size_t)s5.w * F))[lane];
        a0 += bf2f(u0.x) + bf2f(u1.x) + bf2f(u2.x) + bf2f(u3.x)
            + bf2f(u4.x) + bf2f(u5.x) + bf2f(u6.x) + bf2f(u7.x);
        a1 += bf2f(u0.y) + bf2f(u1.y) + bf2f(u2.y) + bf2f(u3.y)
            + bf2f(u4.y) + bf2f(u5.y) + bf2f(u6.y) + bf2f(u7.y);
        a2 += bf2f(u0.z) + bf2f(u1.z) + bf2f(u2.z) + bf2f(u3.z)
            + bf2f(u4.z) + bf2f(u5.z) + bf2f(u6.z) + bf2f(u7.z);
        a3 += bf2f(u0.w) + bf2f(u1.w) + bf2f(u2.w) + bf2f(u3.w)
            + bf2f(u4.w) + bf2f(u5.w) + bf2f(u6.w) + bf2f(u7.w);
    }
    for (; i + 4 <= deg; i += 4) {
        int4 s4 = *(const int4*)(bk + i);
        ushort4 u0 = ((const ushort4*)(H + (size_t)s4.x * F))[lane];
        ushort4 u1 = ((const ushort4*)(H + (size_t)s4.y * F))[lane];
        ushort4 u2 = ((const ushort4*)(H + (size_t)s4.z * F))[lane];
        ushort4 u3 = ((const ushort4*)(H + (size_t)s4.w * F))[lane];
        a0 += bf2f(u0.x) + bf2f(u1.x) + bf2f(u2.x) + bf2f(u3.x);
        a1 += bf2f(u0.y) + bf2f(u1.y) + bf2f(u2.y) + bf2f(u3.y);
        a2 += bf2f(u0.z) + bf2f(u1.z) + bf2f(u2.z) + bf2f(u3.z);
        a3 += bf2f(u0.w) + bf2f(u1.w) + bf2f(u2.w) + bf2f(u3.w);
    }
    for (; i < deg; ++i) {
        ushort4 uv = ((const ushort4*)(H + (size_t)bk[i] * F))[lane];
        a0 += bf2f(uv.x); a1 += bf2f(uv.y); a2 += bf2f(uv.z); a3 += bf2f(uv.w);
    }

    // reduce sd partials across the half-wave
#pragma unroll
    for (int o = 16; o; o >>= 1) sdi += __shfl_xor(sdi, o);
    float sdn = (float)sdi;
    float dn = (float)(deg_t + 1);
    float4 v1v = ((const float4*)v1)[lane];
    float4 bcv = ((const float4*)bc)[lane];
    a0 += sdn * v1v.x + dn * bcv.x;
    a1 += sdn * v1v.y + dn * bcv.y;
    a2 += sdn * v1v.z + dn * bcv.z;
    a3 += sdn * v1v.w + dn * bcv.w;

    float m = fmaxf(fmaxf(a0, a1), fmaxf(a2, a3));
#pragma unroll
    for (int o = 16; o; o >>= 1) m = fmaxf(m, __shfl_xor(m, o));
    float s = expf(a0 - m) + expf(a1 - m) + expf(a2 - m) + expf(a3 - m);
#pragma unroll
    for (int o = 16; o; o >>= 1) s += __shfl_xor(s, o);
    float lse = m + logf(s);
    float4 o4;
    o4.x = a0 - lse; o4.y = a1 - lse; o4.z = a2 - lse; o4.w = a3 - lse;
    ((float4*)(O + (size_t)node * F))[lane] = o4;
}

extern "C" void kernel_launch(void* const* d_in, const int* in_sizes, int n_in,
                              void* d_out, int out_size, void* d_ws, size_t ws_size,
                              hipStream_t stream) {
    const float* x  = (const float*)d_in[0];
    const int* ei   = (const int*)d_in[1];
    const float* w1 = (const float*)d_in[2];
    const float* b1 = (const float*)d_in[3];
    const float* w2 = (const float*)d_in[4];
    const float* b2 = (const float*)d_in[5];
    float* out = (float*)d_out;

    const int* src = ei;
    const int* dst = ei + N_EDGES;

    // workspace layout (float offsets, 16B aligned)
    float* ws     = (float*)d_ws;
    float* Wc     = ws;                          // 16384
    float* bc     = ws + 16384;                  // 128
    float* v1     = ws + 16512;                  // 128
    bf16_t* Mbf   = (bf16_t*)(ws + 16640);       // 16384 bf16 (8192 f)
    int*   cnt    = (int*)(ws + 24832);          // 50048
    int*   bucket = (int*)(ws + 74880);          // 3,200,000
    bf16_t* g     = (bf16_t*)(ws + 3274880);     // 6.4M bf16
    bf16_t* a1    = (bf16_t*)(ws + 6474880);     // 6.4M bf16

    const int gemm_grid = (N_NODES + 63) / 64;                 // 782
    const size_t gemm_lds = (64 + 128) * 128 * sizeof(bf16_t); // 48KB
    const int fill_grid = (N_EDGES + 255) / 256;
    const int node_grid = (N_NODES + 7) / 8;                   // 6250

    k_fuse<<<128, 128, 0, stream>>>(w1, b1, w2, b2, Wc, bc, cnt);
    k_fuse2<<<128, 128, 0, stream>>>(Wc, bc, Mbf, v1);
    k_fill<<<fill_grid, 256, 0, stream>>>(src, dst, cnt, bucket);

    // g = x * M  (bf16 MFMA)
    k_gemm_mfma<<<gemm_grid, 256, gemm_lds, stream>>>(x, Mbf, g, N_NODES);
    // a1 = S * g
    k_agg<<<node_grid, 256, 0, stream>>>(g, cnt, bucket, a1, N_NODES);
    // out = log_softmax(S * a1 + sd*v1^T + d*bc^T), sd inline
    k_agg_ep<<<node_grid, 256, 0, stream>>>(a1, cnt, bucket, v1, bc, out, N_NODES);
}

// Round 6
// 121.053 us; speedup vs baseline: 17.6608x; 1.0473x over previous
//
#include <hip/hip_runtime.h>
#include <hip/hip_bf16.h>

#define N_NODES 50000
#define N_EDGES 600000
#define F 128
#define BCAP 64    // per-node incoming-edge bucket capacity (P(deg>64) ~ 0)

#define GEMM_BLOCKS 782   // ceil(50000/64)
#define FILL_BLOCKS 2344  // ceil(600000/256)

typedef unsigned short bf16_t;
typedef __attribute__((ext_vector_type(8))) short short8v;
typedef __attribute__((ext_vector_type(8))) unsigned short ushort8v;
typedef __attribute__((ext_vector_type(4))) float f32x4;

__device__ inline float bf2f(bf16_t u) {
    union { unsigned int i; float f; } c;
    c.i = ((unsigned int)u) << 16;
    return c.f;
}
__device__ inline bf16_t f2bf(float f) {  // round-to-nearest-even
    union { float f; unsigned int i; } c;
    c.f = f;
    unsigned int lsb = (c.i >> 16) & 1;
    c.i += 0x7fffu + lsb;
    return (bf16_t)(c.i >> 16);
}

// ---------------------------------------------------------------------------
// Stage 1 of weight fusion: Wc = w2 @ w1 (plain [p][j]), bc = w2@b1 + b2.
// Also zeroes cnt[] (replaces a 42us rocclr fillBuffer dispatch).
// ---------------------------------------------------------------------------
__global__ void k_fuse(const float* __restrict__ w1, const float* __restrict__ b1,
                       const float* __restrict__ w2, const float* __restrict__ b2,
                       float* __restrict__ Wc, float* __restrict__ bc,
                       int* __restrict__ cnt) {
    int p = blockIdx.x;
    int j = threadIdx.x;
    int gid = p * 128 + j;
    for (int i = gid; i < N_NODES; i += 128 * 128) cnt[i] = 0;

    float s = 0.f;
    for (int o = 0; o < F; ++o) s = fmaf(w2[p * F + o], w1[o * F + j], s);
    Wc[p * F + j] = s;
    if (j == 0) {
        float t = b2[p];
        for (int o = 0; o < F; ++o) t = fmaf(w2[p * F + o], b1[o], t);
        bc[p] = t;
    }
}

// ---------------------------------------------------------------------------
// Stage 2: Mbf[p][k] = (W^T W^T)[k][p] in bf16 (B-operand layout for MFMA),
//          v1[p] = sum_o Wc[p][o] * bc[o].
// ---------------------------------------------------------------------------
__global__ void k_fuse2(const float* __restrict__ Wc, const float* __restrict__ bc,
                        bf16_t* __restrict__ Mbf, float* __restrict__ v1) {
    int k = blockIdx.x;
    int p = threadIdx.x;
    float s = 0.f;
    for (int o = 0; o < F; ++o) s = fmaf(Wc[p * F + o], Wc[o * F + k], s);
    Mbf[p * F + k] = f2bf(s);   // [p][k]: contiguous along k for B fragments
    if (k == 0) {
        float t = 0.f;
        for (int o = 0; o < F; ++o) t = fmaf(Wc[p * F + o], bc[o], t);
        v1[p] = t;
    }
}

// ---------------------------------------------------------------------------
// Heterogeneous kernel: blocks [0, GEMM_BLOCKS) run the MFMA GEMM g = x*M;
// blocks [GEMM_BLOCKS, GEMM_BLOCKS+FILL_BLOCKS) run the bucket-CSR fill.
// The two roles touch disjoint buffers, so they overlap on the device.
// GEMM keeps only the 16KB swizzled X tile in LDS; B fragments come straight
// from global (M is 32KB, L1/L2-resident, shared by all blocks) so the fill
// blocks' occupancy isn't throttled by a big LDS allocation.
// ---------------------------------------------------------------------------
__global__ __launch_bounds__(256, 4)
void k_main(const float* __restrict__ X, const bf16_t* __restrict__ Mbf,
            bf16_t* __restrict__ G,
            const int* __restrict__ src, const int* __restrict__ dst,
            int* __restrict__ cnt, unsigned short* __restrict__ bucket) {
    const int bid = blockIdx.x;
    const int tid = threadIdx.x;

    if (bid >= GEMM_BLOCKS) {
        // ---- fill role ----
        int e = (bid - GEMM_BLOCKS) * 256 + tid;
        if (e < N_EDGES) {
            int d = dst[e];
            int slot = atomicAdd(&cnt[d], 1);
            if (slot < BCAP) bucket[d * BCAP + slot] = (unsigned short)src[e];
        }
        return;
    }

    // ---- GEMM role ----
    __shared__ unsigned short Xs[64 * 128];  // bf16, swizzled
    const int row0 = bid * 64;

    for (int idx = tid; idx < 1024; idx += 256) {
        int r = idx >> 4, c = idx & 15;
        int grow = row0 + r;
        float4 va = {0.f, 0.f, 0.f, 0.f}, vb = {0.f, 0.f, 0.f, 0.f};
        if (grow < N_NODES) {
            const float4* xr = (const float4*)(X + (size_t)grow * F);
            va = xr[2 * c];
            vb = xr[2 * c + 1];
        }
        ushort8v u;
        u[0] = f2bf(va.x); u[1] = f2bf(va.y); u[2] = f2bf(va.z); u[3] = f2bf(va.w);
        u[4] = f2bf(vb.x); u[5] = f2bf(vb.y); u[6] = f2bf(vb.z); u[7] = f2bf(vb.w);
        *(ushort8v*)&Xs[r * 128 + (((c ^ (r & 7)) << 3))] = u;
    }
    __syncthreads();

    const int wid = tid >> 6;
    const int lane = tid & 63;
    const int wr = wid >> 1;       // wave row (0..1)
    const int wc = wid & 1;        // wave col (0..1)
    const int l15 = lane & 15;
    const int l4 = lane >> 4;
    const int sw = (l15 & 7);

    f32x4 acc[2][4] = {};

#pragma unroll
    for (int kc = 0; kc < 4; ++kc) {
        const int cS = ((kc * 4 + l4) ^ sw) << 3;
        short8v a0 = *(const short8v*)&Xs[(wr * 32 + 0 * 16 + l15) * 128 + cS];
        short8v a1 = *(const short8v*)&Xs[(wr * 32 + 1 * 16 + l15) * 128 + cS];
        // B fragments direct from global: row = col of M-hat, contiguous k
        const bf16_t* mb = Mbf + (size_t)(wc * 64 + l15) * F + kc * 32 + 8 * l4;
        short8v b0 = *(const short8v*)(mb + 0 * 16 * F);
        short8v b1 = *(const short8v*)(mb + 1 * 16 * F);
        short8v b2 = *(const short8v*)(mb + 2 * 16 * F);
        short8v b3 = *(const short8v*)(mb + 3 * 16 * F);
        acc[0][0] = __builtin_amdgcn_mfma_f32_16x16x32_bf16(a0, b0, acc[0][0], 0, 0, 0);
        acc[0][1] = __builtin_amdgcn_mfma_f32_16x16x32_bf16(a0, b1, acc[0][1], 0, 0, 0);
        acc[0][2] = __builtin_amdgcn_mfma_f32_16x16x32_bf16(a0, b2, acc[0][2], 0, 0, 0);
        acc[0][3] = __builtin_amdgcn_mfma_f32_16x16x32_bf16(a0, b3, acc[0][3], 0, 0, 0);
        acc[1][0] = __builtin_amdgcn_mfma_f32_16x16x32_bf16(a1, b0, acc[1][0], 0, 0, 0);
        acc[1][1] = __builtin_amdgcn_mfma_f32_16x16x32_bf16(a1, b1, acc[1][1], 0, 0, 0);
        acc[1][2] = __builtin_amdgcn_mfma_f32_16x16x32_bf16(a1, b2, acc[1][2], 0, 0, 0);
        acc[1][3] = __builtin_amdgcn_mfma_f32_16x16x32_bf16(a1, b3, acc[1][3], 0, 0, 0);
    }

#pragma unroll
    for (int mt = 0; mt < 2; ++mt) {
#pragma unroll
        for (int nt = 0; nt < 4; ++nt) {
#pragma unroll
            for (int r = 0; r < 4; ++r) {
                int grow = row0 + wr * 32 + mt * 16 + l4 * 4 + r;
                if (grow < N_NODES) {
                    int gcol = wc * 64 + nt * 16 + l15;
                    G[(size_t)grow * F + gcol] = f2bf(acc[mt][nt][r]);
                }
            }
        }
    }
}

// ---------------------------------------------------------------------------
// O[n] = H[n] + sum_{s in bucket[n]} H[s].  Half-wave (32 lanes) per node,
// lane holds 4 cols (ushort4 = 8B -> 256B row per half-wave), unroll 8.
// ---------------------------------------------------------------------------
__global__ __launch_bounds__(256)
void k_agg(const bf16_t* __restrict__ H, const int* __restrict__ cnt,
           const unsigned short* __restrict__ bucket, bf16_t* __restrict__ O,
           int n_rows) {
    int tid = threadIdx.x;
    int lane = tid & 31;
    int node = blockIdx.x * 8 + (tid >> 5);
    if (node >= n_rows) return;

    int deg = cnt[node];
    if (deg > BCAP) deg = BCAP;
    ushort4 u = ((const ushort4*)(H + (size_t)node * F))[lane];
    float a0 = bf2f(u.x), a1 = bf2f(u.y), a2 = bf2f(u.z), a3 = bf2f(u.w);

    const unsigned short* bk = bucket + node * BCAP;
    int i = 0;
    for (; i + 8 <= deg; i += 8) {
        ushort8v s8 = *(const ushort8v*)(bk + i);
        ushort4 u0 = ((const ushort4*)(H + (size_t)s8[0] * F))[lane];
        ushort4 u1 = ((const ushort4*)(H + (size_t)s8[1] * F))[lane];
        ushort4 u2 = ((const ushort4*)(H + (size_t)s8[2] * F))[lane];
        ushort4 u3 = ((const ushort4*)(H + (size_t)s8[3] * F))[lane];
        ushort4 u4 = ((const ushort4*)(H + (size_t)s8[4] * F))[lane];
        ushort4 u5 = ((const ushort4*)(H + (size_t)s8[5] * F))[lane];
        ushort4 u6 = ((const ushort4*)(H + (size_t)s8[6] * F))[lane];
        ushort4 u7 = ((const ushort4*)(H + (size_t)s8[7] * F))[lane];
        a0 += bf2f(u0.x) + bf2f(u1.x) + bf2f(u2.x) + bf2f(u3.x)
            + bf2f(u4.x) + bf2f(u5.x) + bf2f(u6.x) + bf2f(u7.x);
        a1 += bf2f(u0.y) + bf2f(u1.y) + bf2f(u2.y) + bf2f(u3.y)
            + bf2f(u4.y) + bf2f(u5.y) + bf2f(u6.y) + bf2f(u7.y);
        a2 += bf2f(u0.z) + bf2f(u1.z) + bf2f(u2.z) + bf2f(u3.z)
            + bf2f(u4.z) + bf2f(u5.z) + bf2f(u6.z) + bf2f(u7.z);
        a3 += bf2f(u0.w) + bf2f(u1.w) + bf2f(u2.w) + bf2f(u3.w)
            + bf2f(u4.w) + bf2f(u5.w) + bf2f(u6.w) + bf2f(u7.w);
    }
    for (; i + 4 <= deg; i += 4) {
        ushort4 s4 = *(const ushort4*)(bk + i);
        ushort4 u0 = ((const ushort4*)(H + (size_t)s4.x * F))[lane];
        ushort4 u1 = ((const ushort4*)(H + (size_t)s4.y * F))[lane];
        ushort4 u2 = ((const ushort4*)(H + (size_t)s4.z * F))[lane];
        ushort4 u3 = ((const ushort4*)(H + (size_t)s4.w * F))[lane];
        a0 += bf2f(u0.x) + bf2f(u1.x) + bf2f(u2.x) + bf2f(u3.x);
        a1 += bf2f(u0.y) + bf2f(u1.y) + bf2f(u2.y) + bf2f(u3.y);
        a2 += bf2f(u0.z) + bf2f(u1.z) + bf2f(u2.z) + bf2f(u3.z);
        a3 += bf2f(u0.w) + bf2f(u1.w) + bf2f(u2.w) + bf2f(u3.w);
    }
    for (; i < deg; ++i) {
        ushort4 uv = ((const ushort4*)(H + (size_t)bk[i] * F))[lane];
        a0 += bf2f(uv.x); a1 += bf2f(uv.y); a2 += bf2f(uv.z); a3 += bf2f(uv.w);
    }
    ushort4 o;
    o.x = f2bf(a0); o.y = f2bf(a1); o.z = f2bf(a2); o.w = f2bf(a3);
    ((ushort4*)(O + (size_t)node * F))[lane] = o;
}

// ---------------------------------------------------------------------------
// Final: out[n] = log_softmax( (S*H)[n] + sd_n*v1 + d_n*bc ).  sd_n computed
// inline (lanes gather cnt over the bucket, shuffle-reduced).
// ---------------------------------------------------------------------------
__global__ __launch_bounds__(256)
void k_agg_ep(const bf16_t* __restrict__ H, const int* __restrict__ cnt,
              const unsigned short* __restrict__ bucket,
              const float* __restrict__ v1, const float* __restrict__ bc,
              float* __restrict__ O, int n_rows) {
    int tid = threadIdx.x;
    int lane = tid & 31;
    int node = blockIdx.x * 8 + (tid >> 5);
    if (node >= n_rows) return;

    int deg_t = cnt[node];
    int deg = deg_t < BCAP ? deg_t : BCAP;
    ushort4 u = ((const ushort4*)(H + (size_t)node * F))[lane];
    float a0 = bf2f(u.x), a1 = bf2f(u.y), a2 = bf2f(u.z), a3 = bf2f(u.w);

    const unsigned short* bk = bucket + node * BCAP;

    int sdi = (lane == 0) ? (deg_t + 1) : 0;
    for (int j = lane; j < deg; j += 32) sdi += cnt[bk[j]] + 1;

    int i = 0;
    for (; i + 8 <= deg; i += 8) {
        ushort8v s8 = *(const ushort8v*)(bk + i);
        ushort4 u0 = ((const ushort4*)(H + (size_t)s8[0] * F))[lane];
        ushort4 u1 = ((const ushort4*)(H + (size_t)s8[1] * F))[lane];
        ushort4 u2 = ((const ushort4*)(H + (size_t)s8[2] * F))[lane];
        ushort4 u3 = ((const ushort4*)(H + (size_t)s8[3] * F))[lane];
        ushort4 u4 = ((const ushort4*)(H + (size_t)s8[4] * F))[lane];
        ushort4 u5 = ((const ushort4*)(H + (size_t)s8[5] * F))[lane];
        ushort4 u6 = ((const ushort4*)(H + (size_t)s8[6] * F))[lane];
        ushort4 u7 = ((const ushort4*)(H + (size_t)s8[7] * F))[lane];
        a0 += bf2f(u0.x) + bf2f(u1.x) + bf2f(u2.x) + bf2f(u3.x)
            + bf2f(u4.x) + bf2f(u5.x) + bf2f(u6.x) + bf2f(u7.x);
        a1 += bf2f(u0.y) + bf2f(u1.y) + bf2f(u2.y) + bf2f(u3.y)
            + bf2f(u4.y) + bf2f(u5.y) + bf2f(u6.y) + bf2f(u7.y);
        a2 += bf2f(u0.z) + bf2f(u1.z) + bf2f(u2.z) + bf2f(u3.z)
            + bf2f(u4.z) + bf2f(u5.z) + bf2f(u6.z) + bf2f(u7.z);
        a3 += bf2f(u0.w) + bf2f(u1.w) + bf2f(u2.w) + bf2f(u3.w)
            + bf2f(u4.w) + bf2f(u5.w) + bf2f(u6.w) + bf2f(u7.w);
    }
    for (; i + 4 <= deg; i += 4) {
        ushort4 s4 = *(const ushort4*)(bk + i);
        ushort4 u0 = ((const ushort4*)(H + (size_t)s4.x * F))[lane];
        ushort4 u1 = ((const ushort4*)(H + (size_t)s4.y * F))[lane];
        ushort4 u2 = ((const ushort4*)(H + (size_t)s4.z * F))[lane];
        ushort4 u3 = ((const ushort4*)(H + (size_t)s4.w * F))[lane];
        a0 += bf2f(u0.x) + bf2f(u1.x) + bf2f(u2.x) + bf2f(u3.x);
        a1 += bf2f(u0.y) + bf2f(u1.y) + bf2f(u2.y) + bf2f(u3.y);
        a2 += bf2f(u0.z) + bf2f(u1.z) + bf2f(u2.z) + bf2f(u3.z);
        a3 += bf2f(u0.w) + bf2f(u1.w) + bf2f(u2.w) + bf2f(u3.w);
    }
    for (; i < deg; ++i) {
        ushort4 uv = ((const ushort4*)(H + (size_t)bk[i] * F))[lane];
        a0 += bf2f(uv.x); a1 += bf2f(uv.y); a2 += bf2f(uv.z); a3 += bf2f(uv.w);
    }

#pragma unroll
    for (int o = 16; o; o >>= 1) sdi += __shfl_xor(sdi, o);
    float sdn = (float)sdi;
    float dn = (float)(deg_t + 1);
    float4 v1v = ((const float4*)v1)[lane];
    float4 bcv = ((const float4*)bc)[lane];
    a0 += sdn * v1v.x + dn * bcv.x;
    a1 += sdn * v1v.y + dn * bcv.y;
    a2 += sdn * v1v.z + dn * bcv.z;
    a3 += sdn * v1v.w + dn * bcv.w;

    float m = fmaxf(fmaxf(a0, a1), fmaxf(a2, a3));
#pragma unroll
    for (int o = 16; o; o >>= 1) m = fmaxf(m, __shfl_xor(m, o));
    float s = expf(a0 - m) + expf(a1 - m) + expf(a2 - m) + expf(a3 - m);
#pragma unroll
    for (int o = 16; o; o >>= 1) s += __shfl_xor(s, o);
    float lse = m + logf(s);
    float4 o4;
    o4.x = a0 - lse; o4.y = a1 - lse; o4.z = a2 - lse; o4.w = a3 - lse;
    ((float4*)(O + (size_t)node * F))[lane] = o4;
}

extern "C" void kernel_launch(void* const* d_in, const int* in_sizes, int n_in,
                              void* d_out, int out_size, void* d_ws, size_t ws_size,
                              hipStream_t stream) {
    const float* x  = (const float*)d_in[0];
    const int* ei   = (const int*)d_in[1];
    const float* w1 = (const float*)d_in[2];
    const float* b1 = (const float*)d_in[3];
    const float* w2 = (const float*)d_in[4];
    const float* b2 = (const float*)d_in[5];
    float* out = (float*)d_out;

    const int* src = ei;
    const int* dst = ei + N_EDGES;

    // workspace layout (float offsets, 16B aligned)
    float* ws        = (float*)d_ws;
    float* Wc        = ws;                              // 16384
    float* bc        = ws + 16384;                      // 128
    float* v1        = ws + 16512;                      // 128
    bf16_t* Mbf      = (bf16_t*)(ws + 16640);           // 16384 bf16 (8192 f)
    int*   cnt       = (int*)(ws + 24832);              // 50048
    unsigned short* bucket = (unsigned short*)(ws + 74880);  // 3.2M u16 (1.6M f)
    bf16_t* g        = (bf16_t*)(ws + 1674880);         // 6.4M bf16 (3.2M f)
    bf16_t* a1       = (bf16_t*)(ws + 4874880);         // 6.4M bf16

    const int node_grid = (N_NODES + 7) / 8;  // 6250

    k_fuse<<<128, 128, 0, stream>>>(w1, b1, w2, b2, Wc, bc, cnt);
    k_fuse2<<<128, 128, 0, stream>>>(Wc, bc, Mbf, v1);

    // overlapped: g = x*M (MFMA)  ||  bucket-CSR fill
    k_main<<<GEMM_BLOCKS + FILL_BLOCKS, 256, 0, stream>>>(x, Mbf, g, src, dst,
                                                          cnt, bucket);
    // a1 = S * g
    k_agg<<<node_grid, 256, 0, stream>>>(g, cnt, bucket, a1, N_NODES);
    // out = log_softmax(S * a1 + sd*v1^T + d*bc^T), sd inline
    k_agg_ep<<<node_grid, 256, 0, stream>>>(a1, cnt, bucket, v1, bc, out, N_NODES);
}